// Round 3
// baseline (304.361 us; speedup 1.0000x reference)
//
#include <hip/hip_runtime.h>
#include <hip/hip_bf16.h>

// Problem constants (fixed): bs=4, S=1024, d_model=512, HEAD=8, D_Q=64
#define BS 4
#define SEQ 1024
#define DM 512
#define EPS 1e-9f
#define SQRTEPS 3.16227766e-5f

typedef __attribute__((ext_vector_type(8))) short short8;   // 8 bf16
typedef __attribute__((ext_vector_type(4))) float floatx4;

// pack 2 f32 -> 1 u32 of 2 bf16 (RNE, v_cvt_pk_bf16_f32)
__device__ __forceinline__ unsigned int pk2(float x, float y) {
    __hip_bfloat162 h = __float22bfloat162_rn(float2{x, y});
    return *reinterpret_cast<unsigned int*>(&h);
}
__device__ __forceinline__ uint4 pk8(floatx4 a, floatx4 b) {
    uint4 r;
    r.x = pk2(a.x, a.y); r.y = pk2(a.z, a.w);
    r.z = pk2(b.x, b.y); r.w = pk2(b.z, b.w);
    return r;
}

// Streaming constant-fill of phrasal background: n_iters x (nthr x 4) floats.
// Nontemporal: 128 MiB of constant background must not evict ctx/CA from L2.
__device__ __forceinline__ void bgwrite(float* base, int n_iters, int tid, int nthr) {
    floatx4 v4 = {SQRTEPS, SQRTEPS, SQRTEPS, SQRTEPS};
    for (int j = 0; j < n_iters; ++j)
        __builtin_nontemporal_store(v4, (floatx4*)(base + (size_t)(j * nthr + tid) * 4));
}

// ---------------------------------------------------------------------------
// Kernel 1: fused f32 staging + projection + neighbor dots. 512 compute
// blocks = (row-tile rt 0..63) x (head h 0..7). Loads ctx/Wq/Wk as f32 and
// converts to bf16 in-register (v_cvt_pk_bf16_f32) during LDS staging --
// no separate convert kernel, no bf16 workspace round-trip. Each block
// computes q,k tiles [64x64] (bias included), then the 63 in-tile neighbor
// dots:  u[i]=q_i.k_{i+1}/512, v[i]=q_{i+1}.k_i/512  for i = rt*64+p, p<63.
// Boundary rows (0 and 63) exported to edge buffers for gscan.
// No QK matrix is ever materialized. +2816 bg writer blocks (88 MB phrasal).
// ---------------------------------------------------------------------------
#define NGEMM 512
#define LDW 72     // staging stride (ushorts)
#define LDQ 65     // qS/kS stride (floats)

__global__ __launch_bounds__(256) void gemmdot_kernel(
    const float* __restrict__ ctx, const float* __restrict__ Wq,
    const float* __restrict__ Wk,
    const float* __restrict__ bq, const float* __restrict__ bk,
    float* __restrict__ uA, float* __restrict__ vA,
    float* __restrict__ qF, float* __restrict__ kF,
    float* __restrict__ qL, float* __restrict__ kL,
    float* __restrict__ phrasal)
{
    __shared__ char smem[2 * 64 * LDQ * 4];            // 33280 B (union)
    unsigned short* Xs  = (unsigned short*)smem;       // 64 x LDW
    unsigned short* Wqs = Xs + 64 * LDW;
    unsigned short* Wks = Wqs + 64 * LDW;
    float* qS = (float*)smem;                          // 64 x LDQ (overlaps staging)
    float* kS = qS + 64 * LDQ;

    const int blk = blockIdx.x, tid = threadIdx.x;
    if (blk >= NGEMM) {
        bgwrite(phrasal + (size_t)(blk - NGEMM) * 8192, 8, tid, 256); // chunks 0..2815
        return;
    }

    const int rt = blk >> 3, h = blk & 7;
    const int wv = tid >> 6, lane = tid & 63;
    const int lr = lane & 15, kg = lane >> 4;

    // staging: thread handles rows r0, r0+32; 8 contiguous cols at kc0
    const int r0 = tid >> 3, kc0 = (tid & 7) << 3;
    const float* Xb  = ctx + (size_t)(rt * 64) * DM;
    const float* Wqb = Wq  + (size_t)(h * 64) * DM;
    const float* Wkb = Wk  + (size_t)(h * 64) * DM;

    floatx4 acc_q[4] = {}, acc_k[4] = {};

    for (int k0 = 0; k0 < DM; k0 += 64) {
        const size_t o0 = (size_t)r0 * DM + k0 + kc0;
        const size_t o1 = (size_t)(r0 + 32) * DM + k0 + kc0;
        floatx4 x0a  = *(const floatx4*)(Xb  + o0);
        floatx4 x0b  = *(const floatx4*)(Xb  + o0 + 4);
        floatx4 x1a  = *(const floatx4*)(Xb  + o1);
        floatx4 x1b  = *(const floatx4*)(Xb  + o1 + 4);
        floatx4 wq0a = *(const floatx4*)(Wqb + o0);
        floatx4 wq0b = *(const floatx4*)(Wqb + o0 + 4);
        floatx4 wq1a = *(const floatx4*)(Wqb + o1);
        floatx4 wq1b = *(const floatx4*)(Wqb + o1 + 4);
        floatx4 wk0a = *(const floatx4*)(Wkb + o0);
        floatx4 wk0b = *(const floatx4*)(Wkb + o0 + 4);
        floatx4 wk1a = *(const floatx4*)(Wkb + o1);
        floatx4 wk1b = *(const floatx4*)(Wkb + o1 + 4);
        __syncthreads();
        *(uint4*)(Xs  + r0 * LDW + kc0)        = pk8(x0a, x0b);
        *(uint4*)(Xs  + (r0 + 32) * LDW + kc0) = pk8(x1a, x1b);
        *(uint4*)(Wqs + r0 * LDW + kc0)        = pk8(wq0a, wq0b);
        *(uint4*)(Wqs + (r0 + 32) * LDW + kc0) = pk8(wq1a, wq1b);
        *(uint4*)(Wks + r0 * LDW + kc0)        = pk8(wk0a, wk0b);
        *(uint4*)(Wks + (r0 + 32) * LDW + kc0) = pk8(wk1a, wk1b);
        __syncthreads();
        #pragma unroll
        for (int ks = 0; ks < 2; ++ks) {
            short8 a = *(const short8*)(Xs + (wv * 16 + lr) * LDW + ks * 32 + kg * 8);
            #pragma unroll
            for (int ni = 0; ni < 4; ++ni) {
                short8 bqf = *(const short8*)(Wqs + (ni * 16 + lr) * LDW + ks * 32 + kg * 8);
                acc_q[ni] = __builtin_amdgcn_mfma_f32_16x16x32_bf16(a, bqf, acc_q[ni], 0, 0, 0);
                short8 bkf = *(const short8*)(Wks + (ni * 16 + lr) * LDW + ks * 32 + kg * 8);
                acc_k[ni] = __builtin_amdgcn_mfma_f32_16x16x32_bf16(a, bkf, acc_k[ni], 0, 0, 0);
            }
        }
    }

    // epilogue: C/D layout col = lane&15 (=lr), row = kg*4 + reg, tile row += 16*wv
    __syncthreads();   // staging reads done before qS/kS overwrite
    #pragma unroll
    for (int ni = 0; ni < 4; ++ni) {
        float bqv = bq[h * 64 + ni * 16 + lr];
        float bkv = bk[h * 64 + ni * 16 + lr];
        #pragma unroll
        for (int r = 0; r < 4; ++r) {
            int row = wv * 16 + kg * 4 + r;
            qS[row * LDQ + ni * 16 + lr] = acc_q[ni][r] + bqv;
            kS[row * LDQ + ni * 16 + lr] = acc_k[ni][r] + bkv;
        }
    }
    __syncthreads();

    // export edge rows (0 and 63) for boundary dots in gscan
    const int eb = (rt * 8 + h) * 64;
    if (tid < 64) {
        qF[eb + tid] = qS[tid];
        kF[eb + tid] = kS[tid];
    } else if (tid >= 192) {
        int l = tid - 192;
        qL[eb + l] = qS[63 * LDQ + l];
        kL[eb + l] = kS[63 * LDQ + l];
    }

    // in-tile neighbor dots: wave wv handles p = wv, wv+4, ...
    for (int p = wv; p < 63; p += 4) {
        float pu = qS[p * LDQ + lane] * kS[(p + 1) * LDQ + lane];
        float pv = qS[(p + 1) * LDQ + lane] * kS[p * LDQ + lane];
        #pragma unroll
        for (int m = 1; m < 64; m <<= 1) {
            pu += __shfl_xor(pu, m);
            pv += __shfl_xor(pv, m);
        }
        if (lane == 0) {
            int r = rt * 64 + p;
            int idx = (((r >> 10) * 8 + h) << 10) | (r & 1023);
            uA[idx] = pu * (1.0f / DM);
            vA[idx] = pv * (1.0f / DM);
        }
    }
}

// ---------------------------------------------------------------------------
// Kernel 2: boundary dots + tridiagonal softmax -> g + exclusive log-scan.
// Blocks 0..31 = (b,h), 1024 threads. +1280 bg writer blocks (40 MB).
// ---------------------------------------------------------------------------
__global__ __launch_bounds__(1024) void gscan_kernel(
    const float* __restrict__ uA, const float* __restrict__ vA,
    const float* __restrict__ qF, const float* __restrict__ kF,
    const float* __restrict__ qL, const float* __restrict__ kL,
    const int* __restrict__ am, float* __restrict__ gA, float* __restrict__ CA,
    float* __restrict__ phrasal)
{
    __shared__ float uS[SEQ], vS[SEQ];
    __shared__ float uFix[16], vFix[16];
    __shared__ double wsum[16];

    const int blk = blockIdx.x, i = threadIdx.x;
    if (blk >= 32) {
        bgwrite(phrasal + (size_t)(2816 + blk - 32) * 8192, 2, i, 1024); // 2816..4095
        return;
    }

    const int bh = blk, b = bh >> 3, h = bh & 7;
    const int base = bh * SEQ;
    const int wv = i >> 6, lane = i & 63;

    // stage u,v (boundary slots i%64==63 hold garbage, patched below)
    uS[i] = uA[base + i];
    vS[i] = vA[base + i];

    // boundary dots: wave j<15 computes pair i = 64j+63 (crosses tiles j, j+1)
    if (wv < 15) {
        int e0 = ((b * 16 + wv) * 8 + h) * 64;   // tile rt = b*16+wv
        int e1 = e0 + 8 * 64;                    // tile rt+1
        float pu = qL[e0 + lane] * kF[e1 + lane];
        float pv = qF[e1 + lane] * kL[e0 + lane];
        #pragma unroll
        for (int m = 1; m < 64; m <<= 1) {
            pu += __shfl_xor(pu, m);
            pv += __shfl_xor(pv, m);
        }
        if (lane == 0) { uFix[wv] = pu * (1.0f / DM); vFix[wv] = pv * (1.0f / DM); }
    }
    __syncthreads();
    if ((i & 63) == 63) {
        int j = i >> 6;
        uS[i] = (j < 15) ? uFix[j] : 0.f;   // i==1023: u,v unused, zero for safety
        vS[i] = (j < 15) ? vFix[j] : 0.f;
    }
    __syncthreads();

    // tridiagonal softmax -> g
    float g = 0.f;
    if (i < SEQ - 1) {
        float u = uS[i], vv = vS[i];
        float vm1 = (i > 0) ? vS[i - 1] : 0.f;
        float up1 = uS[i + 1];
        const int* amb = am + b * SEQ;
        int mL = (i > 0) ? amb[i - 1] : 0;
        int mR = amb[i + 1];
        float s_up = mR ? (mL ? 1.f / (1.f + expf(vm1 - u)) : 1.f) : 0.f;
        int mL2 = amb[i];
        int mR2 = (i + 2 < SEQ) ? amb[i + 2] : 0;
        float s_dn = mL2 ? (mR2 ? 1.f / (1.f + expf(up1 - vv)) : 1.f) : 0.f;
        g = sqrtf(s_up * s_dn + EPS);
        gA[base + i] = g;
    }

    // exclusive prefix-sum of log(g+eps), double precision
    double L = (i < SEQ - 1) ? (double)logf(g + EPS) : 0.0;
    double x = L;
    #pragma unroll
    for (int off = 1; off < 64; off <<= 1) {
        double t = __shfl_up(x, off);
        if (lane >= off) x += t;
    }
    if (lane == 63) wsum[wv] = x;
    __syncthreads();
    double pref = 0.0;
    for (int w = 0; w < wv; ++w) pref += wsum[w];
    CA[base + i] = (float)(pref + x - L);
}

// ---------------------------------------------------------------------------
// Kernel 3: attn fill + phrasal band patch. 4096 blocks x 256 threads;
// block = (bh, 8-row chunk). CA row loaded ONCE into registers per block
// (reused 8x). Streams attn rows with nontemporal float4 stores; patches
// the phrasal tri-diagonal band with one aligned float4 store per row
// (idempotent over the SQRTEPS background written by kernels 1-2).
// ---------------------------------------------------------------------------
#define RPB 8   // rows per block

__global__ __launch_bounds__(256) void fill_attn(
    const float* __restrict__ gA, const float* __restrict__ CA,
    float* __restrict__ attn, float* __restrict__ phrasal)
{
    const int blk = blockIdx.x;          // 0..4095
    const int t   = threadIdx.x;
    const int bh  = blk >> 7;            // 128 blocks per (b,h)
    const int i0  = (blk & 127) * RPB;
    const int base = bh * SEQ;
    const int k0 = t * 4;

    // CA row for this bh, held in registers across all 8 rows
    floatx4 c4 = *(const floatx4*)(CA + base + k0);

    for (int r = 0; r < RPB; ++r) {
        const int i = i0 + r;
        const size_t row = ((size_t)bh << 10) | (unsigned)i;
        const float Ci = CA[base + i];

        floatx4 av;
        #pragma unroll
        for (int j = 0; j < 4; ++j) {
            int k = k0 + j;
            float d = (k > i) ? (c4[j] - Ci) : (Ci - c4[j]);
            av[j] = (k == i) ? SQRTEPS : (__expf(d) + EPS);
        }
        __builtin_nontemporal_store(av, (floatx4*)(attn + (row << 10) + k0));

        // phrasal band patch: only threads whose float4 intersects [i-1, i+1]
        if (k0 + 3 >= i - 1 && k0 <= i + 1) {
            const float gm = (i > 0)       ? gA[base + i - 1] : SQRTEPS;  // k == i-1
            const float gp = (i < SEQ - 1) ? gA[base + i]     : SQRTEPS;  // k == i+1
            floatx4 pv;
            #pragma unroll
            for (int j = 0; j < 4; ++j) {
                int k = k0 + j;
                pv[j] = (k == i - 1) ? gm : ((k == i + 1) ? gp : SQRTEPS);
            }
            *(floatx4*)(phrasal + (row << 10) + k0) = pv;
        }
    }
}

// ---------------------------------------------------------------------------
extern "C" void kernel_launch(void* const* d_in, const int* in_sizes, int n_in,
                              void* d_out, int out_size, void* d_ws, size_t ws_size,
                              hipStream_t stream) {
    const float* ctx = (const float*)d_in[0];
    const int*   am  = (const int*)d_in[1];
    const float* Wq  = (const float*)d_in[2];
    const float* bq  = (const float*)d_in[3];
    const float* Wk  = (const float*)d_in[4];
    const float* bk  = (const float*)d_in[5];
    float* out = (float*)d_out;

    char* ws = (char*)d_ws;
    float* uA = (float*)(ws);             // 128 KiB
    float* vA = (float*)(ws +  131072);   // 128 KiB
    float* gA = (float*)(ws +  262144);   // 128 KiB
    float* CA = (float*)(ws +  393216);   // 128 KiB
    float* qF = (float*)(ws +  524288);   // 128 KiB edges
    float* kF = (float*)(ws +  655360);
    float* qL = (float*)(ws +  786432);
    float* kL = (float*)(ws +  917504);

    float* attn_out    = out;
    float* phrasal_out = out + (size_t)BS * 8 * SEQ * SEQ;

    gemmdot_kernel<<<dim3(NGEMM + 2816), 256, 0, stream>>>(
        ctx, Wq, Wk, bq, bk, uA, vA, qF, kF, qL, kL, phrasal_out);
    gscan_kernel<<<dim3(32 + 1280), 1024, 0, stream>>>(
        uA, vA, qF, kF, qL, kL, am, gA, CA, phrasal_out);
    fill_attn<<<dim3(4096), 256, 0, stream>>>(gA, CA, attn_out, phrasal_out);
}

// Round 4
// 291.849 us; speedup vs baseline: 1.0429x; 1.0429x over previous
//
#include <hip/hip_runtime.h>
#include <hip/hip_bf16.h>

// Problem constants (fixed): bs=4, S=1024, d_model=512, HEAD=8, D_Q=64
#define BS 4
#define SEQ 1024
#define DM 512
#define EPS 1e-9f
#define SQRTEPS 3.16227766e-5f

typedef __attribute__((ext_vector_type(8))) short short8;   // 8 bf16
typedef __attribute__((ext_vector_type(4))) float floatx4;

__device__ __forceinline__ unsigned short f2bf(float x) {
    unsigned int u = __float_as_uint(x);
    return (unsigned short)((u + 0x7fffu + ((u >> 16) & 1u)) >> 16);
}

// Streaming constant-fill of phrasal background: n_iters x (nthr x 4) floats.
// Nontemporal: 128 MiB of constant background must not evict Xbf/Wbf/ctx
// from L2 while gemmdot is re-reading them.
__device__ __forceinline__ void bgwrite(float* base, int n_iters, int tid, int nthr) {
    floatx4 v4 = {SQRTEPS, SQRTEPS, SQRTEPS, SQRTEPS};
    for (int j = 0; j < n_iters; ++j)
        __builtin_nontemporal_store(v4, (floatx4*)(base + (size_t)(j * nthr + tid) * 4));
}

// ---------------------------------------------------------------------------
// Kernel 1: f32->bf16 convert (blocks 0..255, float4-vectorized) + 768 bg
// writer blocks (24 MB phrasal background).
// ---------------------------------------------------------------------------
__global__ __launch_bounds__(256) void convert_kernel(
    const float* __restrict__ ctx, const float* __restrict__ Wq,
    const float* __restrict__ Wk, unsigned short* __restrict__ Xbf,
    unsigned short* __restrict__ Wbf, float* __restrict__ phrasal)
{
    const int blk = blockIdx.x, tid = threadIdx.x;
    if (blk >= 256) {
        bgwrite(phrasal + (size_t)(blk - 256) * 8192, 8, tid, 256);  // chunks 0..767
        return;
    }
    int gthr = blk * 256 + tid;              // 0..65535
    #pragma unroll
    for (int j = 0; j < 10; ++j) {
        int e4 = gthr + 65536 * j;           // float4 index, 655360 total
        int e  = e4 * 4;
        floatx4 s;
        if (e < 2097152) {
            s = *(const floatx4*)(ctx + e);
        } else {
            int e2 = e - 2097152;            // 0..524287
            s = (e2 < 262144) ? *(const floatx4*)(Wq + e2)
                              : *(const floatx4*)(Wk + e2 - 262144);
        }
        ushort2 lo = {f2bf(s.x), f2bf(s.y)}, hi = {f2bf(s.z), f2bf(s.w)};
        unsigned short* dst = (e < 2097152) ? (Xbf + e) : (Wbf + e - 2097152);
        *(ushort2*)dst = lo;
        *(ushort2*)(dst + 2) = hi;
    }
}

// ---------------------------------------------------------------------------
// Kernel 2: fused projection + neighbor dots. 512 compute blocks =
// (row-tile rt 0..63) x (head h 0..7). Each computes q,k tiles [64x64]
// (bias included), then the 63 in-tile neighbor dots:
//   u[i]=q_i.k_{i+1}/512, v[i]=q_{i+1}.k_i/512  for i = rt*64 + p, p<63.
// Boundary rows (0 and 63) exported to edge buffers for gscan.
// No QK matrix is ever materialized. +2048 bg writer blocks (64 MB).
//
// XCD-aware remap: physical block p lands on XCD p%8 (8 XCDs, round-robin).
// Map so the 8 head-blocks sharing one ctx row-tile rt run on the SAME XCD:
// XCD x serves rt in [8x, 8x+8) only -> each Xbf row-tile is read by one
// XCD's L2 (8 hits) instead of being streamed by all 8 XCDs.
// ---------------------------------------------------------------------------
#define NGEMM 512
#define LDW 72     // staging stride (ushorts)
#define LDQ 65     // qS/kS stride (floats)

__global__ __launch_bounds__(256) void gemmdot_kernel(
    const unsigned short* __restrict__ Xbf, const unsigned short* __restrict__ Wbf,
    const float* __restrict__ bq, const float* __restrict__ bk,
    float* __restrict__ uA, float* __restrict__ vA,
    float* __restrict__ qF, float* __restrict__ kF,
    float* __restrict__ qL, float* __restrict__ kL,
    float* __restrict__ phrasal)
{
    __shared__ char smem[2 * 64 * LDQ * 4];            // 33280 B (union)
    unsigned short* Xs  = (unsigned short*)smem;       // 64 x LDW
    unsigned short* Wqs = Xs + 64 * LDW;
    unsigned short* Wks = Wqs + 64 * LDW;
    float* qS = (float*)smem;                          // 64 x LDQ (overlaps staging)
    float* kS = qS + 64 * LDQ;

    const int blk = blockIdx.x, tid = threadIdx.x;
    if (blk >= NGEMM) {
        bgwrite(phrasal + (size_t)(768 + blk - NGEMM) * 8192, 8, tid, 256); // 768..2815
        return;
    }

    // XCD-locality remap (bijective over 0..511): x=blk&7 is the XCD,
    // j=blk>>3 enumerates that XCD's 64 blocks as (rt-sub, head).
    const int xcd = blk & 7, j = blk >> 3;
    const int rt = xcd * 8 + (j & 7), h = j >> 3;
    const int wv = tid >> 6, lane = tid & 63;
    const int lr = lane & 15, kg = lane >> 4;

    // staging: chunk c covers row=c>>3, kc=(c&7)*8; thread handles c=tid, tid+256
    const int r0 = tid >> 3, kc0 = (tid & 7) << 3;
    const unsigned short* Xb  = Xbf + (size_t)(rt * 64) * DM;
    const unsigned short* Wqb = Wbf + (size_t)(h * 64) * DM;
    const unsigned short* Wkb = Wbf + 262144 + (size_t)(h * 64) * DM;

    floatx4 acc_q[4] = {}, acc_k[4] = {};

    for (int k0 = 0; k0 < DM; k0 += 64) {
        uint4 x0  = *(const uint4*)(Xb  + (size_t)r0 * DM + k0 + kc0);
        uint4 x1  = *(const uint4*)(Xb  + (size_t)(r0 + 32) * DM + k0 + kc0);
        uint4 wq0 = *(const uint4*)(Wqb + (size_t)r0 * DM + k0 + kc0);
        uint4 wq1 = *(const uint4*)(Wqb + (size_t)(r0 + 32) * DM + k0 + kc0);
        uint4 wk0 = *(const uint4*)(Wkb + (size_t)r0 * DM + k0 + kc0);
        uint4 wk1 = *(const uint4*)(Wkb + (size_t)(r0 + 32) * DM + k0 + kc0);
        __syncthreads();
        *(uint4*)(Xs  + r0 * LDW + kc0)        = x0;
        *(uint4*)(Xs  + (r0 + 32) * LDW + kc0) = x1;
        *(uint4*)(Wqs + r0 * LDW + kc0)        = wq0;
        *(uint4*)(Wqs + (r0 + 32) * LDW + kc0) = wq1;
        *(uint4*)(Wks + r0 * LDW + kc0)        = wk0;
        *(uint4*)(Wks + (r0 + 32) * LDW + kc0) = wk1;
        __syncthreads();
        #pragma unroll
        for (int ks = 0; ks < 2; ++ks) {
            short8 a = *(const short8*)(Xs + (wv * 16 + lr) * LDW + ks * 32 + kg * 8);
            #pragma unroll
            for (int ni = 0; ni < 4; ++ni) {
                short8 bqf = *(const short8*)(Wqs + (ni * 16 + lr) * LDW + ks * 32 + kg * 8);
                acc_q[ni] = __builtin_amdgcn_mfma_f32_16x16x32_bf16(a, bqf, acc_q[ni], 0, 0, 0);
                short8 bkf = *(const short8*)(Wks + (ni * 16 + lr) * LDW + ks * 32 + kg * 8);
                acc_k[ni] = __builtin_amdgcn_mfma_f32_16x16x32_bf16(a, bkf, acc_k[ni], 0, 0, 0);
            }
        }
    }

    // epilogue: C/D layout col = lane&15 (=lr), row = kg*4 + reg, tile row += 16*wv
    __syncthreads();   // staging reads done before qS/kS overwrite
    #pragma unroll
    for (int ni = 0; ni < 4; ++ni) {
        float bqv = bq[h * 64 + ni * 16 + lr];
        float bkv = bk[h * 64 + ni * 16 + lr];
        #pragma unroll
        for (int r = 0; r < 4; ++r) {
            int row = wv * 16 + kg * 4 + r;
            qS[row * LDQ + ni * 16 + lr] = acc_q[ni][r] + bqv;
            kS[row * LDQ + ni * 16 + lr] = acc_k[ni][r] + bkv;
        }
    }
    __syncthreads();

    // export edge rows (0 and 63) for boundary dots in gscan
    const int eb = (rt * 8 + h) * 64;
    if (tid < 64) {
        qF[eb + tid] = qS[tid];
        kF[eb + tid] = kS[tid];
    } else if (tid >= 192) {
        int l = tid - 192;
        qL[eb + l] = qS[63 * LDQ + l];
        kL[eb + l] = kS[63 * LDQ + l];
    }

    // in-tile neighbor dots: wave wv handles p = wv, wv+4, ...
    for (int p = wv; p < 63; p += 4) {
        float pu = qS[p * LDQ + lane] * kS[(p + 1) * LDQ + lane];
        float pv = qS[(p + 1) * LDQ + lane] * kS[p * LDQ + lane];
        #pragma unroll
        for (int m = 1; m < 64; m <<= 1) {
            pu += __shfl_xor(pu, m);
            pv += __shfl_xor(pv, m);
        }
        if (lane == 0) {
            int r = rt * 64 + p;
            int idx = (((r >> 10) * 8 + h) << 10) | (r & 1023);
            uA[idx] = pu * (1.0f / DM);
            vA[idx] = pv * (1.0f / DM);
        }
    }
}

// ---------------------------------------------------------------------------
// Kernel 3: boundary dots + tridiagonal softmax -> g + exclusive log-scan.
// Blocks 0..31 = (b,h), 1024 threads. +1280 bg writer blocks (40 MB).
// ---------------------------------------------------------------------------
__global__ __launch_bounds__(1024) void gscan_kernel(
    const float* __restrict__ uA, const float* __restrict__ vA,
    const float* __restrict__ qF, const float* __restrict__ kF,
    const float* __restrict__ qL, const float* __restrict__ kL,
    const int* __restrict__ am, float* __restrict__ gA, float* __restrict__ CA,
    float* __restrict__ phrasal)
{
    __shared__ float uS[SEQ], vS[SEQ];
    __shared__ float uFix[16], vFix[16];
    __shared__ double wsum[16];

    const int blk = blockIdx.x, i = threadIdx.x;
    if (blk >= 32) {
        bgwrite(phrasal + (size_t)(2816 + blk - 32) * 8192, 2, i, 1024); // 2816..4095
        return;
    }

    const int bh = blk, b = bh >> 3, h = bh & 7;
    const int base = bh * SEQ;
    const int wv = i >> 6, lane = i & 63;

    // stage u,v (boundary slots i%64==63 hold garbage, patched below)
    uS[i] = uA[base + i];
    vS[i] = vA[base + i];

    // boundary dots: wave j<15 computes pair i = 64j+63 (crosses tiles j, j+1)
    if (wv < 15) {
        int e0 = ((b * 16 + wv) * 8 + h) * 64;   // tile rt = b*16+wv
        int e1 = e0 + 8 * 64;                    // tile rt+1
        float pu = qL[e0 + lane] * kF[e1 + lane];
        float pv = qF[e1 + lane] * kL[e0 + lane];
        #pragma unroll
        for (int m = 1; m < 64; m <<= 1) {
            pu += __shfl_xor(pu, m);
            pv += __shfl_xor(pv, m);
        }
        if (lane == 0) { uFix[wv] = pu * (1.0f / DM); vFix[wv] = pv * (1.0f / DM); }
    }
    __syncthreads();
    if ((i & 63) == 63) {
        int j = i >> 6;
        uS[i] = (j < 15) ? uFix[j] : 0.f;   // i==1023: u,v unused, zero for safety
        vS[i] = (j < 15) ? vFix[j] : 0.f;
    }
    __syncthreads();

    // tridiagonal softmax -> g
    float g = 0.f;
    if (i < SEQ - 1) {
        float u = uS[i], vv = vS[i];
        float vm1 = (i > 0) ? vS[i - 1] : 0.f;
        float up1 = uS[i + 1];
        const int* amb = am + b * SEQ;
        int mL = (i > 0) ? amb[i - 1] : 0;
        int mR = amb[i + 1];
        float s_up = mR ? (mL ? 1.f / (1.f + expf(vm1 - u)) : 1.f) : 0.f;
        int mL2 = amb[i];
        int mR2 = (i + 2 < SEQ) ? amb[i + 2] : 0;
        float s_dn = mL2 ? (mR2 ? 1.f / (1.f + expf(up1 - vv)) : 1.f) : 0.f;
        g = sqrtf(s_up * s_dn + EPS);
        gA[base + i] = g;
    }

    // exclusive prefix-sum of log(g+eps), double precision
    double L = (i < SEQ - 1) ? (double)logf(g + EPS) : 0.0;
    double x = L;
    #pragma unroll
    for (int off = 1; off < 64; off <<= 1) {
        double t = __shfl_up(x, off);
        if (lane >= off) x += t;
    }
    if (lane == 63) wsum[wv] = x;
    __syncthreads();
    double pref = 0.0;
    for (int w = 0; w < wv; ++w) pref += wsum[w];
    CA[base + i] = (float)(pref + x - L);
}

// ---------------------------------------------------------------------------
// Kernel 4: attn fill + phrasal off-diagonal fix-up. One block per (bh,i) row.
// (R0's best-measured fill configuration, unchanged.)
// ---------------------------------------------------------------------------
__global__ __launch_bounds__(256) void fill_attn(
    const float* __restrict__ gA, const float* __restrict__ CA,
    float* __restrict__ attn, float* __restrict__ phrasal)
{
    const int row = blockIdx.x;           // bh*1024 + i
    const int bh  = row >> 10;
    const int i   = row & 1023;
    const int t   = threadIdx.x;

    const float Ci = CA[row];
    floatx4 c4 = *(const floatx4*)(CA + bh * SEQ + t * 4);
    floatx4 av;
    #pragma unroll
    for (int j = 0; j < 4; ++j) {
        int k = t * 4 + j;
        float d = (k > i) ? (c4[j] - Ci) : (Ci - c4[j]);
        av[j] = (k == i) ? SQRTEPS : (__expf(d) + EPS);
    }
    *(floatx4*)(attn + (size_t)row * SEQ + t * 4) = av;

    if (t == 0 && i > 0)
        phrasal[(size_t)row * SEQ + i - 1] = gA[bh * SEQ + i - 1];
    if (t == 1 && i < SEQ - 1)
        phrasal[(size_t)row * SEQ + i + 1] = gA[bh * SEQ + i];
}

// ---------------------------------------------------------------------------
extern "C" void kernel_launch(void* const* d_in, const int* in_sizes, int n_in,
                              void* d_out, int out_size, void* d_ws, size_t ws_size,
                              hipStream_t stream) {
    const float* ctx = (const float*)d_in[0];
    const int*   am  = (const int*)d_in[1];
    const float* Wq  = (const float*)d_in[2];
    const float* bq  = (const float*)d_in[3];
    const float* Wk  = (const float*)d_in[4];
    const float* bk  = (const float*)d_in[5];
    float* out = (float*)d_out;

    char* ws = (char*)d_ws;
    unsigned short* Xbf = (unsigned short*)(ws);                 //  4 MiB
    unsigned short* Wbf = (unsigned short*)(ws + 4194304);       //  1 MiB
    float*          uA  = (float*)(ws + 5242880);                // 128 KiB
    float*          vA  = (float*)(ws + 5373952);                // 128 KiB
    float*          gA  = (float*)(ws + 5505024);                // 128 KiB
    float*          CA  = (float*)(ws + 5636096);                // 128 KiB
    float*          qF  = (float*)(ws + 5767168);                // 128 KiB edges
    float*          kF  = (float*)(ws + 5898240);
    float*          qL  = (float*)(ws + 6029312);
    float*          kL  = (float*)(ws + 6160384);

    float* attn_out    = out;
    float* phrasal_out = out + (size_t)BS * 8 * SEQ * SEQ;

    convert_kernel<<<dim3(256 + 768), 256, 0, stream>>>(ctx, Wq, Wk, Xbf, Wbf, phrasal_out);
    gemmdot_kernel<<<dim3(NGEMM + 2048), 256, 0, stream>>>(
        Xbf, Wbf, bq, bk, uA, vA, qF, kF, qL, kL, phrasal_out);
    gscan_kernel<<<dim3(32 + 1280), 1024, 0, stream>>>(
        uA, vA, qF, kF, qL, kL, am, gA, CA, phrasal_out);
    fill_attn<<<dim3(BS * 8 * SEQ), 256, 0, stream>>>(gA, CA, attn_out, phrasal_out);
}